// Round 10
// baseline (411.786 us; speedup 1.0000x reference)
//
#include <hip/hip_runtime.h>

#define AS1 __attribute__((address_space(1)))
#define AS3 __attribute__((address_space(3)))

typedef __bf16 bf16x8 __attribute__((ext_vector_type(8)));
typedef float f32x4 __attribute__((ext_vector_type(4)));

__device__ __forceinline__ unsigned short f2bf(float f) {
  unsigned int u = __builtin_bit_cast(unsigned int, f);
  u += 0x7fffu + ((u >> 16) & 1u);   // round-to-nearest-even
  return (unsigned short)(u >> 16);
}

// ---------------------------------------------------------------------------
// Transpose K/V (f32, [b,t,h*256+j]) -> bf16 tiles [pp][s][j:256][t:32]
// ---------------------------------------------------------------------------
__global__ __launch_bounds__(256) void kv_transpose(
    const float* __restrict__ key, const float* __restrict__ value,
    unsigned short* __restrict__ KT2, unsigned short* __restrict__ VT2) {
  __shared__ float tr[32 * 33];
  const int tid = threadIdx.x;
  const int ts  = blockIdx.y;          // 0 = K, 1 = V
  const int pp  = blockIdx.x >> 3;
  const int s   = blockIdx.x & 7;
  const int b   = ts ? (pp >> 4) : (pp & 15);
  const int h   = ts ? (pp & 15) : (pp >> 4);
  const float* src = (ts ? value : key) + ((size_t)(b * 256 + s * 32)) * 4096 + h * 256;
  unsigned short* dst = (ts ? VT2 : KT2) + (size_t)(pp * 8 + s) * 8192;
  const int tt = tid >> 3;   // 0..31
  const int q8 = tid & 7;    // 0..7
  for (int jb = 0; jb < 8; ++jb) {
    float4 v = *(const float4*)(src + (size_t)tt * 4096 + jb * 32 + q8 * 4);
    tr[tt * 33 + q8 * 4 + 0] = v.x;
    tr[tt * 33 + q8 * 4 + 1] = v.y;
    tr[tt * 33 + q8 * 4 + 2] = v.z;
    tr[tt * 33 + q8 * 4 + 3] = v.w;
    __syncthreads();
    ushort4 o;
    o.x = f2bf(tr[(q8 * 4 + 0) * 33 + tt]);
    o.y = f2bf(tr[(q8 * 4 + 1) * 33 + tt]);
    o.z = f2bf(tr[(q8 * 4 + 2) * 33 + tt]);
    o.w = f2bf(tr[(q8 * 4 + 3) * 33 + tt]);
    *(ushort4*)(dst + (jb * 32 + tt) * 32 + q8 * 4) = o;
    __syncthreads();
  }
}

// ---------------------------------------------------------------------------
// Attention (validated).
// ---------------------------------------------------------------------------
__global__ __launch_bounds__(256, 2) void attn_kernel(
    const float* __restrict__ qin, const unsigned short* __restrict__ KT2,
    const unsigned short* __restrict__ VT2, unsigned short* __restrict__ attn) {
  __shared__ __align__(16) unsigned short kv[8192];
  __shared__ __align__(16) unsigned short plds[4 * 16 * 264];

  const int tid  = threadIdx.x;
  const int lane = tid & 63;
  const int wave = tid >> 6;
  const int li   = lane & 15;
  const int ks   = lane >> 4;

  const int bid = blockIdx.x;
  const int pp  = (bid & 7) * 32 + ((bid >> 3) & 31);
  const int ib  = bid >> 8;
  const int x = pp >> 4, y = pp & 15;
  const int i0 = ib * 64 + wave * 16;

  bf16x8 qf[8];
  {
    const float* qrow = qin + ((size_t)(y * 256 + i0 + li)) * 4096 + x * 256 + ks * 8;
#pragma unroll
    for (int s = 0; s < 8; ++s) {
      float4 v0 = *(const float4*)(qrow + s * 32);
      float4 v1 = *(const float4*)(qrow + s * 32 + 4);
      union { bf16x8 v; unsigned short u[8]; } t;
      t.u[0] = f2bf(v0.x * 0.0625f); t.u[1] = f2bf(v0.y * 0.0625f);
      t.u[2] = f2bf(v0.z * 0.0625f); t.u[3] = f2bf(v0.w * 0.0625f);
      t.u[4] = f2bf(v1.x * 0.0625f); t.u[5] = f2bf(v1.y * 0.0625f);
      t.u[6] = f2bf(v1.z * 0.0625f); t.u[7] = f2bf(v1.w * 0.0625f);
      qf[s] = t.v;
    }
  }

  const f32x4 vzero = {0.f, 0.f, 0.f, 0.f};
  f32x4 sacc[16];
#pragma unroll
  for (int f = 0; f < 16; ++f) sacc[f] = vzero;

  const unsigned short* ktile = KT2 + (size_t)pp * 65536;
#pragma unroll
  for (int s = 0; s < 8; ++s) {
    __syncthreads();
#pragma unroll
    for (int cc = 0; cc < 4; ++cc) {
      const unsigned short* g = ktile + (size_t)s * 8192 + (cc * 256 + tid) * 8;
      __builtin_amdgcn_global_load_lds((AS1 unsigned int*)g,
          (AS3 unsigned int*)((AS3 char*)kv + cc * 4096 + wave * 1024), 16, 0, 0);
    }
    __syncthreads();
#pragma unroll
    for (int f = 0; f < 16; ++f) {
      bf16x8 bfr = *(const bf16x8*)&kv[(f * 16 + li) * 32 + ks * 8];
      sacc[f] = __builtin_amdgcn_mfma_f32_16x16x32_bf16(qf[s], bfr, sacc[f], 0, 0, 0);
    }
  }

  float sm[4];
#pragma unroll
  for (int qi = 0; qi < 4; ++qi) {
    float m = sacc[0][qi];
#pragma unroll
    for (int f = 1; f < 16; ++f) m = fmaxf(m, sacc[f][qi]);
    m = fmaxf(m, __shfl_xor(m, 1));
    m = fmaxf(m, __shfl_xor(m, 2));
    m = fmaxf(m, __shfl_xor(m, 4));
    m = fmaxf(m, __shfl_xor(m, 8));
    float ssum = 0.f;
#pragma unroll
    for (int f = 0; f < 16; ++f) {
      float pv = __expf(sacc[f][qi] - m);
      sacc[f][qi] = pv;
      ssum += pv;
    }
    ssum += __shfl_xor(ssum, 1);
    ssum += __shfl_xor(ssum, 2);
    ssum += __shfl_xor(ssum, 4);
    ssum += __shfl_xor(ssum, 8);
    sm[qi] = ssum;
  }

  unsigned short* pw = plds + wave * 4224;
#pragma unroll
  for (int f = 0; f < 16; ++f)
#pragma unroll
    for (int qi = 0; qi < 4; ++qi)
      pw[(ks * 4 + qi) * 264 + f * 16 + li] = f2bf(sacc[f][qi]);

  f32x4 oacc[16];
#pragma unroll
  for (int f = 0; f < 16; ++f) oacc[f] = vzero;
  const unsigned short* vtile = VT2 + (size_t)pp * 65536;
  const unsigned short* pr = plds + wave * 4224 + li * 264;
#pragma unroll
  for (int s2 = 0; s2 < 8; ++s2) {
    __syncthreads();
#pragma unroll
    for (int cc = 0; cc < 4; ++cc) {
      const unsigned short* g = vtile + (size_t)s2 * 8192 + (cc * 256 + tid) * 8;
      __builtin_amdgcn_global_load_lds((AS1 unsigned int*)g,
          (AS3 unsigned int*)((AS3 char*)kv + cc * 4096 + wave * 1024), 16, 0, 0);
    }
    __syncthreads();
    bf16x8 afr = *(const bf16x8*)&pr[s2 * 32 + ks * 8];
#pragma unroll
    for (int f = 0; f < 16; ++f) {
      bf16x8 bfr = *(const bf16x8*)&kv[(f * 16 + li) * 32 + ks * 8];
      oacc[f] = __builtin_amdgcn_mfma_f32_16x16x32_bf16(afr, bfr, oacc[f], 0, 0, 0);
    }
  }

  float rs4[4];
#pragma unroll
  for (int qi = 0; qi < 4; ++qi) rs4[qi] = 1.0f / sm[qi];
  unsigned short* abase = attn + (size_t)(x * 256 + i0 + ks * 4) * 4096 + y * 256 + li;
#pragma unroll
  for (int f = 0; f < 16; ++f)
#pragma unroll
    for (int qi = 0; qi < 4; ++qi)
      abase[(size_t)qi * 4096 + f * 16] = f2bf(oacc[f][qi] * rs4[qi]);
}

// ---------------------------------------------------------------------------
// out_w f32 -> bf16
// ---------------------------------------------------------------------------
__global__ __launch_bounds__(256) void convw(const float* __restrict__ w,
                                             unsigned short* __restrict__ o) {
  const int i = blockIdx.x * 256 + threadIdx.x;
  const float4* s = (const float4*)w + (size_t)i * 2;
  float4 v0 = s[0], v1 = s[1];
  uint4 pk;
  pk.x = (unsigned)f2bf(v0.x) | ((unsigned)f2bf(v0.y) << 16);
  pk.y = (unsigned)f2bf(v0.z) | ((unsigned)f2bf(v0.w) << 16);
  pk.z = (unsigned)f2bf(v1.x) | ((unsigned)f2bf(v1.y) << 16);
  pk.w = (unsigned)f2bf(v1.z) | ((unsigned)f2bf(v1.w) << 16);
  *((uint4*)o + i) = pk;
}

// ---------------------------------------------------------------------------
// 256x256xBK=32 GEMM. R10: A-operand DIRECT FROM GLOBAL (register dbuf, one
// tile ahead); only B goes through LDS (ring-3 x 16KB). Rationale (R9 pm):
// LDS port needed ~1540 cyc/tile (96KB reads + 32KB DMA writes) > MFMA 1242
// -> port was the co-bottleneck in every schedule. Now port = 48KB ~ 565 cyc
// << MFMA. A L2 traffic 64KB/tile/CU ~ 50 B/cyc < 135 ceiling; XCD x owns
// A panels mi in {2x,2x+1} (disjoint across XCDs -> A HBM-fetched once,
// L2-resident K-slices). One barrier/tile. vmcnt(2) end-of-tile is
// order-robust: drains all but the 2 newest issues; the B batch being
// certified is a full tile older.
// ---------------------------------------------------------------------------
__global__ __launch_bounds__(512, 2) void proj_gemm_ag(
    const unsigned short* __restrict__ A, const unsigned short* __restrict__ W,
    const float* __restrict__ bias, float* __restrict__ out) {
  __shared__ __align__(1024) char lds[49152];   // 3 slots x 16KB (B only)

  const int tid  = threadIdx.x;
  const int lane = tid & 63;
  const int w    = tid >> 6;
  const int li   = lane & 15;
  const int ks   = lane >> 4;
  const int wr   = w >> 2;          // 0..1 (M half)
  const int wc   = w & 3;           // 0..3 (N quarter)
  // proven-0-conflict B read base: 64B rows, XOR row-bit3 into bank bit5
  const int LB   = (li * 64 + ks * 16) ^ (((li >> 3) & 1) << 5);

  const int bid = blockIdx.x;
  const int x8  = bid & 7, jj = bid >> 3;
  const int mi  = 2 * x8 + (jj >> 4);              // XCD x owns mi {2x,2x+1}
  const int ni  = jj & 15;
  const int m0b = mi * 256, n0b = ni * 256;

  // B staging: per thread 2 x 16B, linear LDS dest, inverse-swizzled source
  unsigned sB[2];
  int dPB[2];
#pragma unroll
  for (int j2 = 0; j2 < 2; ++j2) {
    int P = j2 * 8192 + tid * 16;
    int L = P ^ (((P >> 9) & 1) << 5);              // involution
    int row = L >> 6, col = L & 63;
    dPB[j2] = P;
    sB[j2] = (unsigned)((n0b + row) * 8192 + col);
  }
  const char* Ac = (const char*)A;
  const char* Wc = (const char*)W;
  AS3 char* L3 = (AS3 char*)lds;

  // A per-lane global base: frag m, K-tile t -> aRow + m*131072 + t*64
  const size_t aRow = (size_t)(m0b + wr * 128 + li) * 8192 + (size_t)ks * 16;

  const f32x4 vzero = {0.f, 0.f, 0.f, 0.f};
  f32x4 acc[8][4];
#pragma unroll
  for (int m = 0; m < 8; ++m)
#pragma unroll
    for (int n = 0; n < 4; ++n) acc[m][n] = vzero;

#define PREF(T, DST) do {                                                      \
    _Pragma("unroll") for (int m = 0; m < 8; ++m)                              \
      DST[m] = *(const bf16x8*)(Ac + aRow + (size_t)m * 131072 +               \
                                (unsigned)(T) * 64u);                          \
  } while (0)
#define STB(T, SL) do {                                                        \
    const unsigned _ko = (unsigned)(T) * 64u;                                  \
    _Pragma("unroll") for (int j2 = 0; j2 < 2; ++j2)                           \
      __builtin_amdgcn_global_load_lds((AS1 unsigned int*)(Wc + sB[j2] + _ko), \
          (AS3 unsigned int*)(L3 + (SL) + dPB[j2]), 16, 0, 0);                 \
  } while (0)
#define MFMA(a, b, c) __builtin_amdgcn_mfma_f32_16x16x32_bf16((a), (b), (c), 0, 0, 0)

  bf16x8 aA[8], aB[8];

  // ---- prologue: B tiles 0,1 -> slots 0,1; A tile 0 -> aA ----
  STB(0, 0); STB(1, 16384);
  PREF(0, aA);
  asm volatile("s_waitcnt vmcnt(0)" ::: "memory");  // one-time full drain
  __builtin_amdgcn_s_barrier();

  int rs = 0, ws = 32768;   // read slot (t%3), write slot ((t+2)%3)

#define TILE(T, AC, AN) do {                                                   \
    bf16x8 bf[4];                                                              \
    _Pragma("unroll") for (int n = 0; n < 4; ++n)                              \
      bf[n] = *(const bf16x8*)(lds + rs + wc * 4096 + n * 1024 + LB);          \
    PREF(((T) + 1 < 128) ? (T) + 1 : 127, AN);                                 \
    STB(((T) + 2 < 128) ? (T) + 2 : 127, ws);                                  \
    __builtin_amdgcn_s_setprio(1);                                             \
    _Pragma("unroll") for (int m = 0; m < 8; ++m)                              \
      _Pragma("unroll") for (int n = 0; n < 4; ++n)                            \
        acc[m][n] = MFMA(AC[m], bf[n], acc[m][n]);                             \
    __builtin_amdgcn_s_setprio(0);                                             \
    asm volatile("s_waitcnt vmcnt(2)" ::: "memory");                           \
    __builtin_amdgcn_s_barrier();                                              \
    rs = (rs == 32768) ? 0 : rs + 16384;                                       \
    ws = (ws == 32768) ? 0 : ws + 16384;                                       \
  } while (0)

  for (int tt = 0; tt < 64; ++tt) {
    TILE(2 * tt,     aA, aB);
    TILE(2 * tt + 1, aB, aA);
  }

  // ---- epilogue ----
  float bv[4];
#pragma unroll
  for (int n = 0; n < 4; ++n) bv[n] = bias[n0b + wc * 64 + n * 16 + li];
#pragma unroll
  for (int m = 0; m < 8; ++m) {
#pragma unroll
    for (int qi = 0; qi < 4; ++qi) {
      const int row = m0b + wr * 128 + m * 16 + ks * 4 + qi;
      float* orow = out + (size_t)row * 4096 + n0b + wc * 64 + li;
#pragma unroll
      for (int n = 0; n < 4; ++n) orow[n * 16] = acc[m][n][qi] + bv[n];
    }
  }
#undef PREF
#undef STB
#undef MFMA
#undef TILE
}

// ---------------------------------------------------------------------------
extern "C" void kernel_launch(void* const* d_in, const int* in_sizes, int n_in,
                              void* d_out, int out_size, void* d_ws, size_t ws_size,
                              hipStream_t stream) {
  const float* q = (const float*)d_in[0];
  const float* k = (const float*)d_in[1];
  const float* v = (const float*)d_in[2];
  const float* w = (const float*)d_in[3];
  const float* b = (const float*)d_in[4];
  float* out = (float*)d_out;
  char* ws = (char*)d_ws;

  unsigned short* attn = (unsigned short*)ws;                      // 32 MB
  unsigned short* KT2  = (unsigned short*)(ws + (size_t)33554432); // 32 MB
  unsigned short* VT2  = (unsigned short*)(ws + (size_t)67108864); // 32 MB
  unsigned short* wbf  = KT2;  // reuse KT2 region after attention is done

  kv_transpose<<<dim3(2048, 2), 256, 0, stream>>>(k, v, KT2, VT2);
  attn_kernel<<<1024, 256, 0, stream>>>(q, KT2, VT2, attn);
  convw<<<8192, 256, 0, stream>>>(w, wbf);
  proj_gemm_ag<<<256, 512, 0, stream>>>(attn, wbf, b, out);
}

// Round 11
// 403.034 us; speedup vs baseline: 1.0217x; 1.0217x over previous
//
#include <hip/hip_runtime.h>

#define AS1 __attribute__((address_space(1)))
#define AS3 __attribute__((address_space(3)))

typedef __bf16 bf16x8 __attribute__((ext_vector_type(8)));
typedef float f32x4 __attribute__((ext_vector_type(4)));

__device__ __forceinline__ unsigned short f2bf(float f) {
  unsigned int u = __builtin_bit_cast(unsigned int, f);
  u += 0x7fffu + ((u >> 16) & 1u);   // round-to-nearest-even
  return (unsigned short)(u >> 16);
}

// ---------------------------------------------------------------------------
// Transpose K/V (f32, [b,t,h*256+j]) -> bf16 tiles [pp][s][j:256][t:32]
// ---------------------------------------------------------------------------
__global__ __launch_bounds__(256) void kv_transpose(
    const float* __restrict__ key, const float* __restrict__ value,
    unsigned short* __restrict__ KT2, unsigned short* __restrict__ VT2) {
  __shared__ float tr[32 * 33];
  const int tid = threadIdx.x;
  const int ts  = blockIdx.y;          // 0 = K, 1 = V
  const int pp  = blockIdx.x >> 3;
  const int s   = blockIdx.x & 7;
  const int b   = ts ? (pp >> 4) : (pp & 15);
  const int h   = ts ? (pp & 15) : (pp >> 4);
  const float* src = (ts ? value : key) + ((size_t)(b * 256 + s * 32)) * 4096 + h * 256;
  unsigned short* dst = (ts ? VT2 : KT2) + (size_t)(pp * 8 + s) * 8192;
  const int tt = tid >> 3;   // 0..31
  const int q8 = tid & 7;    // 0..7
  for (int jb = 0; jb < 8; ++jb) {
    float4 v = *(const float4*)(src + (size_t)tt * 4096 + jb * 32 + q8 * 4);
    tr[tt * 33 + q8 * 4 + 0] = v.x;
    tr[tt * 33 + q8 * 4 + 1] = v.y;
    tr[tt * 33 + q8 * 4 + 2] = v.z;
    tr[tt * 33 + q8 * 4 + 3] = v.w;
    __syncthreads();
    ushort4 o;
    o.x = f2bf(tr[(q8 * 4 + 0) * 33 + tt]);
    o.y = f2bf(tr[(q8 * 4 + 1) * 33 + tt]);
    o.z = f2bf(tr[(q8 * 4 + 2) * 33 + tt]);
    o.w = f2bf(tr[(q8 * 4 + 3) * 33 + tt]);
    *(ushort4*)(dst + (jb * 32 + tt) * 32 + q8 * 4) = o;
    __syncthreads();
  }
}

// ---------------------------------------------------------------------------
// Attention (validated).
// ---------------------------------------------------------------------------
__global__ __launch_bounds__(256, 2) void attn_kernel(
    const float* __restrict__ qin, const unsigned short* __restrict__ KT2,
    const unsigned short* __restrict__ VT2, unsigned short* __restrict__ attn) {
  __shared__ __align__(16) unsigned short kv[8192];
  __shared__ __align__(16) unsigned short plds[4 * 16 * 264];

  const int tid  = threadIdx.x;
  const int lane = tid & 63;
  const int wave = tid >> 6;
  const int li   = lane & 15;
  const int ks   = lane >> 4;

  const int bid = blockIdx.x;
  const int pp  = (bid & 7) * 32 + ((bid >> 3) & 31);
  const int ib  = bid >> 8;
  const int x = pp >> 4, y = pp & 15;
  const int i0 = ib * 64 + wave * 16;

  bf16x8 qf[8];
  {
    const float* qrow = qin + ((size_t)(y * 256 + i0 + li)) * 4096 + x * 256 + ks * 8;
#pragma unroll
    for (int s = 0; s < 8; ++s) {
      float4 v0 = *(const float4*)(qrow + s * 32);
      float4 v1 = *(const float4*)(qrow + s * 32 + 4);
      union { bf16x8 v; unsigned short u[8]; } t;
      t.u[0] = f2bf(v0.x * 0.0625f); t.u[1] = f2bf(v0.y * 0.0625f);
      t.u[2] = f2bf(v0.z * 0.0625f); t.u[3] = f2bf(v0.w * 0.0625f);
      t.u[4] = f2bf(v1.x * 0.0625f); t.u[5] = f2bf(v1.y * 0.0625f);
      t.u[6] = f2bf(v1.z * 0.0625f); t.u[7] = f2bf(v1.w * 0.0625f);
      qf[s] = t.v;
    }
  }

  const f32x4 vzero = {0.f, 0.f, 0.f, 0.f};
  f32x4 sacc[16];
#pragma unroll
  for (int f = 0; f < 16; ++f) sacc[f] = vzero;

  const unsigned short* ktile = KT2 + (size_t)pp * 65536;
#pragma unroll
  for (int s = 0; s < 8; ++s) {
    __syncthreads();
#pragma unroll
    for (int cc = 0; cc < 4; ++cc) {
      const unsigned short* g = ktile + (size_t)s * 8192 + (cc * 256 + tid) * 8;
      __builtin_amdgcn_global_load_lds((AS1 unsigned int*)g,
          (AS3 unsigned int*)((AS3 char*)kv + cc * 4096 + wave * 1024), 16, 0, 0);
    }
    __syncthreads();
#pragma unroll
    for (int f = 0; f < 16; ++f) {
      bf16x8 bfr = *(const bf16x8*)&kv[(f * 16 + li) * 32 + ks * 8];
      sacc[f] = __builtin_amdgcn_mfma_f32_16x16x32_bf16(qf[s], bfr, sacc[f], 0, 0, 0);
    }
  }

  float sm[4];
#pragma unroll
  for (int qi = 0; qi < 4; ++qi) {
    float m = sacc[0][qi];
#pragma unroll
    for (int f = 1; f < 16; ++f) m = fmaxf(m, sacc[f][qi]);
    m = fmaxf(m, __shfl_xor(m, 1));
    m = fmaxf(m, __shfl_xor(m, 2));
    m = fmaxf(m, __shfl_xor(m, 4));
    m = fmaxf(m, __shfl_xor(m, 8));
    float ssum = 0.f;
#pragma unroll
    for (int f = 0; f < 16; ++f) {
      float pv = __expf(sacc[f][qi] - m);
      sacc[f][qi] = pv;
      ssum += pv;
    }
    ssum += __shfl_xor(ssum, 1);
    ssum += __shfl_xor(ssum, 2);
    ssum += __shfl_xor(ssum, 4);
    ssum += __shfl_xor(ssum, 8);
    sm[qi] = ssum;
  }

  unsigned short* pw = plds + wave * 4224;
#pragma unroll
  for (int f = 0; f < 16; ++f)
#pragma unroll
    for (int qi = 0; qi < 4; ++qi)
      pw[(ks * 4 + qi) * 264 + f * 16 + li] = f2bf(sacc[f][qi]);

  f32x4 oacc[16];
#pragma unroll
  for (int f = 0; f < 16; ++f) oacc[f] = vzero;
  const unsigned short* vtile = VT2 + (size_t)pp * 65536;
  const unsigned short* pr = plds + wave * 4224 + li * 264;
#pragma unroll
  for (int s2 = 0; s2 < 8; ++s2) {
    __syncthreads();
#pragma unroll
    for (int cc = 0; cc < 4; ++cc) {
      const unsigned short* g = vtile + (size_t)s2 * 8192 + (cc * 256 + tid) * 8;
      __builtin_amdgcn_global_load_lds((AS1 unsigned int*)g,
          (AS3 unsigned int*)((AS3 char*)kv + cc * 4096 + wave * 1024), 16, 0, 0);
    }
    __syncthreads();
    bf16x8 afr = *(const bf16x8*)&pr[s2 * 32 + ks * 8];
#pragma unroll
    for (int f = 0; f < 16; ++f) {
      bf16x8 bfr = *(const bf16x8*)&kv[(f * 16 + li) * 32 + ks * 8];
      oacc[f] = __builtin_amdgcn_mfma_f32_16x16x32_bf16(afr, bfr, oacc[f], 0, 0, 0);
    }
  }

  float rs4[4];
#pragma unroll
  for (int qi = 0; qi < 4; ++qi) rs4[qi] = 1.0f / sm[qi];
  unsigned short* abase = attn + (size_t)(x * 256 + i0 + ks * 4) * 4096 + y * 256 + li;
#pragma unroll
  for (int f = 0; f < 16; ++f)
#pragma unroll
    for (int qi = 0; qi < 4; ++qi)
      abase[(size_t)qi * 4096 + f * 16] = f2bf(oacc[f][qi] * rs4[qi]);
}

// ---------------------------------------------------------------------------
// out_w f32 -> bf16
// ---------------------------------------------------------------------------
__global__ __launch_bounds__(256) void convw(const float* __restrict__ w,
                                             unsigned short* __restrict__ o) {
  const int i = blockIdx.x * 256 + threadIdx.x;
  const float4* s = (const float4*)w + (size_t)i * 2;
  float4 v0 = s[0], v1 = s[1];
  uint4 pk;
  pk.x = (unsigned)f2bf(v0.x) | ((unsigned)f2bf(v0.y) << 16);
  pk.y = (unsigned)f2bf(v0.z) | ((unsigned)f2bf(v0.w) << 16);
  pk.z = (unsigned)f2bf(v1.x) | ((unsigned)f2bf(v1.y) << 16);
  pk.w = (unsigned)f2bf(v1.z) | ((unsigned)f2bf(v1.w) << 16);
  *((uint4*)o + i) = pk;
}

// ---------------------------------------------------------------------------
// 256x256xBK=32 GEMM, A direct-from-global (register dbuf), B-only LDS ring-3.
// R11 fix vs R10: vmcnt(2) -> vmcnt(10). A-PREF and B-STB share the vmcnt
// counter; per tile 10 ops issue (8 PREF(t+1) + 2 STB(t+2)). vmcnt(2) was
// draining 8 of the 10 JUST-issued ops -> full memory latency exposed every
// tile (R10: MfmaUtil 17.9%). vmcnt(10) keeps all 10 newest in flight and
// certifies exactly STB(t+1) (issued one tile ago) -- true in any issue
// order. Port traffic (B only, 48KB/tile) ~565 cyc << MFMA 1242 -> matrix
// pipe is the sole floor. XCD x owns A panels mi in {2x,2x+1}: A L2-resident,
// HBM-fetched once.
// ---------------------------------------------------------------------------
__global__ __launch_bounds__(512, 2) void proj_gemm_ag(
    const unsigned short* __restrict__ A, const unsigned short* __restrict__ W,
    const float* __restrict__ bias, float* __restrict__ out) {
  __shared__ __align__(1024) char lds[49152];   // 3 slots x 16KB (B only)

  const int tid  = threadIdx.x;
  const int lane = tid & 63;
  const int w    = tid >> 6;
  const int li   = lane & 15;
  const int ks   = lane >> 4;
  const int wr   = w >> 2;          // 0..1 (M half)
  const int wc   = w & 3;           // 0..3 (N quarter)
  // proven-0-conflict B read base: 64B rows, XOR row-bit3 into bank bit5
  const int LB   = (li * 64 + ks * 16) ^ (((li >> 3) & 1) << 5);

  const int bid = blockIdx.x;
  const int x8  = bid & 7, jj = bid >> 3;
  const int mi  = 2 * x8 + (jj >> 4);              // XCD x owns mi {2x,2x+1}
  const int ni  = jj & 15;
  const int m0b = mi * 256, n0b = ni * 256;

  // B staging: per thread 2 x 16B, linear LDS dest, inverse-swizzled source
  unsigned sB[2];
  int dPB[2];
#pragma unroll
  for (int j2 = 0; j2 < 2; ++j2) {
    int P = j2 * 8192 + tid * 16;
    int L = P ^ (((P >> 9) & 1) << 5);              // involution
    int row = L >> 6, col = L & 63;
    dPB[j2] = P;
    sB[j2] = (unsigned)((n0b + row) * 8192 + col);
  }
  const char* Ac = (const char*)A;
  const char* Wc = (const char*)W;
  AS3 char* L3 = (AS3 char*)lds;

  // A per-lane global base: frag m, K-tile t -> aRow + m*131072 + t*64
  const size_t aRow = (size_t)(m0b + wr * 128 + li) * 8192 + (size_t)ks * 16;

  const f32x4 vzero = {0.f, 0.f, 0.f, 0.f};
  f32x4 acc[8][4];
#pragma unroll
  for (int m = 0; m < 8; ++m)
#pragma unroll
    for (int n = 0; n < 4; ++n) acc[m][n] = vzero;

#define PREF(T, DST) do {                                                      \
    _Pragma("unroll") for (int m = 0; m < 8; ++m)                              \
      DST[m] = *(const bf16x8*)(Ac + aRow + (size_t)m * 131072 +               \
                                (unsigned)(T) * 64u);                          \
  } while (0)
#define STB(T, SL) do {                                                        \
    const unsigned _ko = (unsigned)(T) * 64u;                                  \
    _Pragma("unroll") for (int j2 = 0; j2 < 2; ++j2)                           \
      __builtin_amdgcn_global_load_lds((AS1 unsigned int*)(Wc + sB[j2] + _ko), \
          (AS3 unsigned int*)(L3 + (SL) + dPB[j2]), 16, 0, 0);                 \
  } while (0)
#define MFMA(a, b, c) __builtin_amdgcn_mfma_f32_16x16x32_bf16((a), (b), (c), 0, 0, 0)

  bf16x8 aA[8], aB[8];

  // ---- prologue: B tiles 0,1 -> slots 0,1; A tile 0 -> aA ----
  STB(0, 0); STB(1, 16384);
  PREF(0, aA);
  asm volatile("s_waitcnt vmcnt(0)" ::: "memory");  // one-time full drain
  __builtin_amdgcn_s_barrier();

  int rs = 0, ws = 32768;   // read slot (t%3), write slot ((t+2)%3)

  // Per tile: issue STB(t+2) then PREF(t+1) (10 vm ops), MFMA on regs loaded
  // last tile, then vmcnt(10) = keep the 10 newest in flight, certify
  // STB(t+1) -> slot t+1 ready at the barrier.
#define TILE(T, AC, AN) do {                                                   \
    bf16x8 bf[4];                                                              \
    _Pragma("unroll") for (int n = 0; n < 4; ++n)                              \
      bf[n] = *(const bf16x8*)(lds + rs + wc * 4096 + n * 1024 + LB);          \
    STB(((T) + 2 < 128) ? (T) + 2 : 127, ws);                                  \
    PREF(((T) + 1 < 128) ? (T) + 1 : 127, AN);                                 \
    __builtin_amdgcn_s_setprio(1);                                             \
    _Pragma("unroll") for (int m = 0; m < 8; ++m)                              \
      _Pragma("unroll") for (int n = 0; n < 4; ++n)                            \
        acc[m][n] = MFMA(AC[m], bf[n], acc[m][n]);                             \
    __builtin_amdgcn_s_setprio(0);                                             \
    asm volatile("s_waitcnt vmcnt(10)" ::: "memory");                          \
    __builtin_amdgcn_s_barrier();                                              \
    rs = (rs == 32768) ? 0 : rs + 16384;                                       \
    ws = (ws == 32768) ? 0 : ws + 16384;                                       \
  } while (0)

  for (int tt = 0; tt < 64; ++tt) {
    TILE(2 * tt,     aA, aB);
    TILE(2 * tt + 1, aB, aA);
  }

  // ---- epilogue ----
  float bv[4];
#pragma unroll
  for (int n = 0; n < 4; ++n) bv[n] = bias[n0b + wc * 64 + n * 16 + li];
#pragma unroll
  for (int m = 0; m < 8; ++m) {
#pragma unroll
    for (int qi = 0; qi < 4; ++qi) {
      const int row = m0b + wr * 128 + m * 16 + ks * 4 + qi;
      float* orow = out + (size_t)row * 4096 + n0b + wc * 64 + li;
#pragma unroll
      for (int n = 0; n < 4; ++n) orow[n * 16] = acc[m][n][qi] + bv[n];
    }
  }
#undef PREF
#undef STB
#undef MFMA
#undef TILE
}

// ---------------------------------------------------------------------------
extern "C" void kernel_launch(void* const* d_in, const int* in_sizes, int n_in,
                              void* d_out, int out_size, void* d_ws, size_t ws_size,
                              hipStream_t stream) {
  const float* q = (const float*)d_in[0];
  const float* k = (const float*)d_in[1];
  const float* v = (const float*)d_in[2];
  const float* w = (const float*)d_in[3];
  const float* b = (const float*)d_in[4];
  float* out = (float*)d_out;
  char* ws = (char*)d_ws;

  unsigned short* attn = (unsigned short*)ws;                      // 32 MB
  unsigned short* KT2  = (unsigned short*)(ws + (size_t)33554432); // 32 MB
  unsigned short* VT2  = (unsigned short*)(ws + (size_t)67108864); // 32 MB
  unsigned short* wbf  = KT2;  // reuse KT2 region after attention is done

  kv_transpose<<<dim3(2048, 2), 256, 0, stream>>>(k, v, KT2, VT2);
  attn_kernel<<<1024, 256, 0, stream>>>(q, KT2, VT2, attn);
  convw<<<8192, 256, 0, stream>>>(w, wbf);
  proj_gemm_ag<<<256, 512, 0, stream>>>(attn, wbf, b, out);
}

// Round 12
// 230.347 us; speedup vs baseline: 1.7877x; 1.7497x over previous
//
#include <hip/hip_runtime.h>

#define AS1 __attribute__((address_space(1)))
#define AS3 __attribute__((address_space(3)))

typedef __bf16 bf16x8 __attribute__((ext_vector_type(8)));
typedef float f32x4 __attribute__((ext_vector_type(4)));

__device__ __forceinline__ unsigned short f2bf(float f) {
  unsigned int u = __builtin_bit_cast(unsigned int, f);
  u += 0x7fffu + ((u >> 16) & 1u);   // round-to-nearest-even
  return (unsigned short)(u >> 16);
}

// ---------------------------------------------------------------------------
// Transpose K/V (f32, [b,t,h*256+j]) -> bf16 tiles [pp][s][j:256][t:32]
// ---------------------------------------------------------------------------
__global__ __launch_bounds__(256) void kv_transpose(
    const float* __restrict__ key, const float* __restrict__ value,
    unsigned short* __restrict__ KT2, unsigned short* __restrict__ VT2) {
  __shared__ float tr[32 * 33];
  const int tid = threadIdx.x;
  const int ts  = blockIdx.y;          // 0 = K, 1 = V
  const int pp  = blockIdx.x >> 3;
  const int s   = blockIdx.x & 7;
  const int b   = ts ? (pp >> 4) : (pp & 15);
  const int h   = ts ? (pp & 15) : (pp >> 4);
  const float* src = (ts ? value : key) + ((size_t)(b * 256 + s * 32)) * 4096 + h * 256;
  unsigned short* dst = (ts ? VT2 : KT2) + (size_t)(pp * 8 + s) * 8192;
  const int tt = tid >> 3;   // 0..31
  const int q8 = tid & 7;    // 0..7
  for (int jb = 0; jb < 8; ++jb) {
    float4 v = *(const float4*)(src + (size_t)tt * 4096 + jb * 32 + q8 * 4);
    tr[tt * 33 + q8 * 4 + 0] = v.x;
    tr[tt * 33 + q8 * 4 + 1] = v.y;
    tr[tt * 33 + q8 * 4 + 2] = v.z;
    tr[tt * 33 + q8 * 4 + 3] = v.w;
    __syncthreads();
    ushort4 o;
    o.x = f2bf(tr[(q8 * 4 + 0) * 33 + tt]);
    o.y = f2bf(tr[(q8 * 4 + 1) * 33 + tt]);
    o.z = f2bf(tr[(q8 * 4 + 2) * 33 + tt]);
    o.w = f2bf(tr[(q8 * 4 + 3) * 33 + tt]);
    *(ushort4*)(dst + (jb * 32 + tt) * 32 + q8 * 4) = o;
    __syncthreads();
  }
}

// ---------------------------------------------------------------------------
// Attention (validated).
// ---------------------------------------------------------------------------
__global__ __launch_bounds__(256, 2) void attn_kernel(
    const float* __restrict__ qin, const unsigned short* __restrict__ KT2,
    const unsigned short* __restrict__ VT2, unsigned short* __restrict__ attn) {
  __shared__ __align__(16) unsigned short kv[8192];
  __shared__ __align__(16) unsigned short plds[4 * 16 * 264];

  const int tid  = threadIdx.x;
  const int lane = tid & 63;
  const int wave = tid >> 6;
  const int li   = lane & 15;
  const int ks   = lane >> 4;

  const int bid = blockIdx.x;
  const int pp  = (bid & 7) * 32 + ((bid >> 3) & 31);
  const int ib  = bid >> 8;
  const int x = pp >> 4, y = pp & 15;
  const int i0 = ib * 64 + wave * 16;

  bf16x8 qf[8];
  {
    const float* qrow = qin + ((size_t)(y * 256 + i0 + li)) * 4096 + x * 256 + ks * 8;
#pragma unroll
    for (int s = 0; s < 8; ++s) {
      float4 v0 = *(const float4*)(qrow + s * 32);
      float4 v1 = *(const float4*)(qrow + s * 32 + 4);
      union { bf16x8 v; unsigned short u[8]; } t;
      t.u[0] = f2bf(v0.x * 0.0625f); t.u[1] = f2bf(v0.y * 0.0625f);
      t.u[2] = f2bf(v0.z * 0.0625f); t.u[3] = f2bf(v0.w * 0.0625f);
      t.u[4] = f2bf(v1.x * 0.0625f); t.u[5] = f2bf(v1.y * 0.0625f);
      t.u[6] = f2bf(v1.z * 0.0625f); t.u[7] = f2bf(v1.w * 0.0625f);
      qf[s] = t.v;
    }
  }

  const f32x4 vzero = {0.f, 0.f, 0.f, 0.f};
  f32x4 sacc[16];
#pragma unroll
  for (int f = 0; f < 16; ++f) sacc[f] = vzero;

  const unsigned short* ktile = KT2 + (size_t)pp * 65536;
#pragma unroll
  for (int s = 0; s < 8; ++s) {
    __syncthreads();
#pragma unroll
    for (int cc = 0; cc < 4; ++cc) {
      const unsigned short* g = ktile + (size_t)s * 8192 + (cc * 256 + tid) * 8;
      __builtin_amdgcn_global_load_lds((AS1 unsigned int*)g,
          (AS3 unsigned int*)((AS3 char*)kv + cc * 4096 + wave * 1024), 16, 0, 0);
    }
    __syncthreads();
#pragma unroll
    for (int f = 0; f < 16; ++f) {
      bf16x8 bfr = *(const bf16x8*)&kv[(f * 16 + li) * 32 + ks * 8];
      sacc[f] = __builtin_amdgcn_mfma_f32_16x16x32_bf16(qf[s], bfr, sacc[f], 0, 0, 0);
    }
  }

  float sm[4];
#pragma unroll
  for (int qi = 0; qi < 4; ++qi) {
    float m = sacc[0][qi];
#pragma unroll
    for (int f = 1; f < 16; ++f) m = fmaxf(m, sacc[f][qi]);
    m = fmaxf(m, __shfl_xor(m, 1));
    m = fmaxf(m, __shfl_xor(m, 2));
    m = fmaxf(m, __shfl_xor(m, 4));
    m = fmaxf(m, __shfl_xor(m, 8));
    float ssum = 0.f;
#pragma unroll
    for (int f = 0; f < 16; ++f) {
      float pv = __expf(sacc[f][qi] - m);
      sacc[f][qi] = pv;
      ssum += pv;
    }
    ssum += __shfl_xor(ssum, 1);
    ssum += __shfl_xor(ssum, 2);
    ssum += __shfl_xor(ssum, 4);
    ssum += __shfl_xor(ssum, 8);
    sm[qi] = ssum;
  }

  unsigned short* pw = plds + wave * 4224;
#pragma unroll
  for (int f = 0; f < 16; ++f)
#pragma unroll
    for (int qi = 0; qi < 4; ++qi)
      pw[(ks * 4 + qi) * 264 + f * 16 + li] = f2bf(sacc[f][qi]);

  f32x4 oacc[16];
#pragma unroll
  for (int f = 0; f < 16; ++f) oacc[f] = vzero;
  const unsigned short* vtile = VT2 + (size_t)pp * 65536;
  const unsigned short* pr = plds + wave * 4224 + li * 264;
#pragma unroll
  for (int s2 = 0; s2 < 8; ++s2) {
    __syncthreads();
#pragma unroll
    for (int cc = 0; cc < 4; ++cc) {
      const unsigned short* g = vtile + (size_t)s2 * 8192 + (cc * 256 + tid) * 8;
      __builtin_amdgcn_global_load_lds((AS1 unsigned int*)g,
          (AS3 unsigned int*)((AS3 char*)kv + cc * 4096 + wave * 1024), 16, 0, 0);
    }
    __syncthreads();
    bf16x8 afr = *(const bf16x8*)&pr[s2 * 32 + ks * 8];
#pragma unroll
    for (int f = 0; f < 16; ++f) {
      bf16x8 bfr = *(const bf16x8*)&kv[(f * 16 + li) * 32 + ks * 8];
      oacc[f] = __builtin_amdgcn_mfma_f32_16x16x32_bf16(afr, bfr, oacc[f], 0, 0, 0);
    }
  }

  float rs4[4];
#pragma unroll
  for (int qi = 0; qi < 4; ++qi) rs4[qi] = 1.0f / sm[qi];
  unsigned short* abase = attn + (size_t)(x * 256 + i0 + ks * 4) * 4096 + y * 256 + li;
#pragma unroll
  for (int f = 0; f < 16; ++f)
#pragma unroll
    for (int qi = 0; qi < 4; ++qi)
      abase[(size_t)qi * 4096 + f * 16] = f2bf(oacc[f][qi] * rs4[qi]);
}

// ---------------------------------------------------------------------------
// out_w f32 -> bf16
// ---------------------------------------------------------------------------
__global__ __launch_bounds__(256) void convw(const float* __restrict__ w,
                                             unsigned short* __restrict__ o) {
  const int i = blockIdx.x * 256 + threadIdx.x;
  const float4* s = (const float4*)w + (size_t)i * 2;
  float4 v0 = s[0], v1 = s[1];
  uint4 pk;
  pk.x = (unsigned)f2bf(v0.x) | ((unsigned)f2bf(v0.y) << 16);
  pk.y = (unsigned)f2bf(v0.z) | ((unsigned)f2bf(v0.w) << 16);
  pk.z = (unsigned)f2bf(v1.x) | ((unsigned)f2bf(v1.y) << 16);
  pk.w = (unsigned)f2bf(v1.z) | ((unsigned)f2bf(v1.w) << 16);
  *((uint4*)o + i) = pk;
}

// ---------------------------------------------------------------------------
// 256x256xBK=64 GEMM, ring-2 LDS (2 x 64KB), ONE barrier per K-tile (64 total
// vs R7's 128). Proven R7 layout: per-kk region [256 rows][32 bf16] (64B
// rows), XOR swizzle row-bit3<->bank-bit5 (PMC: 0 conflicts). Per tile, two
// sub-phases (kk=0,1), no barrier between:
//   {stage 2 DMA loads of tile t+1 -> other buf; 12 ds_reads (compiler
//    counted-lgkm); 32 MFMA}
// End of tile: vmcnt(0) (drains only stage(t+1), issued ~2500 cyc earlier ->
// cheap) + barrier. Safety: tile t's reads are MFMA-consumed before t's
// barrier; stage at t+1 overwrites the buffer read at t-1 -> race-free.
// ---------------------------------------------------------------------------
__global__ __launch_bounds__(512, 2) void proj_gemm64(
    const unsigned short* __restrict__ A, const unsigned short* __restrict__ W,
    const float* __restrict__ bias, float* __restrict__ out) {
  __shared__ __align__(1024) char lds[131072];  // 2 bufs x (A 32K | B 32K)

  const int tid  = threadIdx.x;
  const int lane = tid & 63;
  const int w    = tid >> 6;
  const int li   = lane & 15;
  const int ks   = lane >> 4;
  const int wr   = w >> 2;          // 0..1 (M half)
  const int wc   = w & 3;           // 0..3 (N quarter)
  const int LB   = (li * 64 + ks * 16) ^ (((li >> 3) & 1) << 5);

  const int bid = blockIdx.x;
  const int swz = (bid & 7) * 32 + (bid >> 3);      // XCD swizzle, 256 % 8 == 0
  const int m0b = (swz >> 4) * 256, n0b = (swz & 15) * 256;

  // staging: thread covers physical bytes {tid*16, 8192+tid*16} of each 16KB
  // kk-region; linear LDS dest + inverse-swizzled global source.
  unsigned sA[2], sB[2];
  int dstP[2];
#pragma unroll
  for (int j = 0; j < 2; ++j) {
    int P = j * 8192 + tid * 16;
    int L = P ^ (((P >> 9) & 1) << 5);              // involution
    int row = L >> 6, col = L & 63;
    dstP[j] = P;
    sA[j] = (unsigned)((m0b + row) * 8192 + col);
    sB[j] = (unsigned)((n0b + row) * 8192 + col);
  }
  const char* Ac = (const char*)A;
  const char* Wc = (const char*)W;
  AS3 char* L3 = (AS3 char*)lds;

  const f32x4 vzero = {0.f, 0.f, 0.f, 0.f};
  f32x4 acc[8][4];
#pragma unroll
  for (int m = 0; m < 8; ++m)
#pragma unroll
    for (int n = 0; n < 4; ++n) acc[m][n] = vzero;

#define STG_A(kt, buf, kk) do {                                                \
    const unsigned _o = (unsigned)(kt) * 128u + (unsigned)(kk) * 64u;          \
    _Pragma("unroll") for (int j = 0; j < 2; ++j)                              \
      __builtin_amdgcn_global_load_lds((AS1 unsigned int*)(Ac + sA[j] + _o),   \
          (AS3 unsigned int*)(L3 + (buf) + (kk) * 16384 + dstP[j]), 16, 0, 0); \
  } while (0)
#define STG_B(kt, buf, kk) do {                                                \
    const unsigned _o = (unsigned)(kt) * 128u + (unsigned)(kk) * 64u;          \
    _Pragma("unroll") for (int j = 0; j < 2; ++j)                              \
      __builtin_amdgcn_global_load_lds((AS1 unsigned int*)(Wc + sB[j] + _o),   \
          (AS3 unsigned int*)(L3 + (buf) + 32768 + (kk) * 16384 + dstP[j]),    \
          16, 0, 0);                                                           \
  } while (0)
#define RD_A(buf, kk, m) (*(const bf16x8*)(lds + (buf) + (kk) * 16384 +        \
                                           wr * 8192 + (m) * 1024 + LB))
#define RD_B(buf, kk, n) (*(const bf16x8*)(lds + (buf) + 32768 + (kk) * 16384 + \
                                           wc * 4096 + (n) * 1024 + LB))
#define MFMA(a, b, c) __builtin_amdgcn_mfma_f32_16x16x32_bf16((a), (b), (c), 0, 0, 0)

  // ---- prologue: tile 0 -> buf 0 ----
  STG_A(0, 0, 0); STG_A(0, 0, 1); STG_B(0, 0, 0); STG_B(0, 0, 1);
  asm volatile("s_waitcnt vmcnt(0)" ::: "memory");
  __builtin_amdgcn_s_barrier();

  for (int t = 0; t < 64; ++t) {
    const int cur = (t & 1) * 65536;
    const int oth = 65536 - cur;
    const int k1  = (t < 63) ? t + 1 : 63;          // clamped tail: dead buf
    bf16x8 af[8], bf[4];

    // ---- sub-phase 0 (kk=0): stage A(t+1); reads; MFMA ----
    STG_A(k1, oth, 0); STG_A(k1, oth, 1);
    af[0] = RD_A(cur, 0, 0);
#pragma unroll
    for (int n = 0; n < 4; ++n) bf[n] = RD_B(cur, 0, n);
#pragma unroll
    for (int m = 1; m < 8; ++m) af[m] = RD_A(cur, 0, m);
    __builtin_amdgcn_s_setprio(1);
#pragma unroll
    for (int m = 0; m < 8; ++m)
#pragma unroll
      for (int n = 0; n < 4; ++n)
        acc[m][n] = MFMA(af[m], bf[n], acc[m][n]);
    __builtin_amdgcn_s_setprio(0);

    // ---- sub-phase 1 (kk=1): stage B(t+1); reads; MFMA ----
    STG_B(k1, oth, 0); STG_B(k1, oth, 1);
    af[0] = RD_A(cur, 1, 0);
#pragma unroll
    for (int n = 0; n < 4; ++n) bf[n] = RD_B(cur, 1, n);
#pragma unroll
    for (int m = 1; m < 8; ++m) af[m] = RD_A(cur, 1, m);
    __builtin_amdgcn_s_setprio(1);
#pragma unroll
    for (int m = 0; m < 8; ++m)
#pragma unroll
      for (int n = 0; n < 4; ++n)
        acc[m][n] = MFMA(af[m], bf[n], acc[m][n]);
    __builtin_amdgcn_s_setprio(0);

    asm volatile("s_waitcnt vmcnt(0)" ::: "memory");  // stage(t+1) complete
    __builtin_amdgcn_s_barrier();
  }

  // ---- epilogue ----
  float bv[4];
#pragma unroll
  for (int n = 0; n < 4; ++n) bv[n] = bias[n0b + wc * 64 + n * 16 + li];
#pragma unroll
  for (int m = 0; m < 8; ++m) {
#pragma unroll
    for (int qi = 0; qi < 4; ++qi) {
      const int row = m0b + wr * 128 + m * 16 + ks * 4 + qi;
      float* orow = out + (size_t)row * 4096 + n0b + wc * 64 + li;
#pragma unroll
      for (int n = 0; n < 4; ++n) orow[n * 16] = acc[m][n][qi] + bv[n];
    }
  }
#undef STG_A
#undef STG_B
#undef RD_A
#undef RD_B
#undef MFMA
}

// ---------------------------------------------------------------------------
extern "C" void kernel_launch(void* const* d_in, const int* in_sizes, int n_in,
                              void* d_out, int out_size, void* d_ws, size_t ws_size,
                              hipStream_t stream) {
  const float* q = (const float*)d_in[0];
  const float* k = (const float*)d_in[1];
  const float* v = (const float*)d_in[2];
  const float* w = (const float*)d_in[3];
  const float* b = (const float*)d_in[4];
  float* out = (float*)d_out;
  char* ws = (char*)d_ws;

  unsigned short* attn = (unsigned short*)ws;                      // 32 MB
  unsigned short* KT2  = (unsigned short*)(ws + (size_t)33554432); // 32 MB
  unsigned short* VT2  = (unsigned short*)(ws + (size_t)67108864); // 32 MB
  unsigned short* wbf  = KT2;  // reuse KT2 region after attention is done

  kv_transpose<<<dim3(2048, 2), 256, 0, stream>>>(k, v, KT2, VT2);
  attn_kernel<<<1024, 256, 0, stream>>>(q, KT2, VT2, attn);
  convw<<<8192, 256, 0, stream>>>(w, wbf);
  proj_gemm64<<<256, 512, 0, stream>>>(attn, wbf, b, out);
}

// Round 13
// 221.585 us; speedup vs baseline: 1.8584x; 1.0395x over previous
//
#include <hip/hip_runtime.h>

#define AS1 __attribute__((address_space(1)))
#define AS3 __attribute__((address_space(3)))

typedef __bf16 bf16x8 __attribute__((ext_vector_type(8)));
typedef float f32x4 __attribute__((ext_vector_type(4)));

__device__ __forceinline__ unsigned short f2bf(float f) {
  unsigned int u = __builtin_bit_cast(unsigned int, f);
  u += 0x7fffu + ((u >> 16) & 1u);   // round-to-nearest-even
  return (unsigned short)(u >> 16);
}

// ---------------------------------------------------------------------------
// Transpose K/V (f32, [b,t,h*256+j]) -> bf16 tiles [pp][s][j:256][t:32]
// ---------------------------------------------------------------------------
__global__ __launch_bounds__(256) void kv_transpose(
    const float* __restrict__ key, const float* __restrict__ value,
    unsigned short* __restrict__ KT2, unsigned short* __restrict__ VT2) {
  __shared__ float tr[32 * 33];
  const int tid = threadIdx.x;
  const int ts  = blockIdx.y;          // 0 = K, 1 = V
  const int pp  = blockIdx.x >> 3;
  const int s   = blockIdx.x & 7;
  const int b   = ts ? (pp >> 4) : (pp & 15);
  const int h   = ts ? (pp & 15) : (pp >> 4);
  const float* src = (ts ? value : key) + ((size_t)(b * 256 + s * 32)) * 4096 + h * 256;
  unsigned short* dst = (ts ? VT2 : KT2) + (size_t)(pp * 8 + s) * 8192;
  const int tt = tid >> 3;   // 0..31
  const int q8 = tid & 7;    // 0..7
  for (int jb = 0; jb < 8; ++jb) {
    float4 v = *(const float4*)(src + (size_t)tt * 4096 + jb * 32 + q8 * 4);
    tr[tt * 33 + q8 * 4 + 0] = v.x;
    tr[tt * 33 + q8 * 4 + 1] = v.y;
    tr[tt * 33 + q8 * 4 + 2] = v.z;
    tr[tt * 33 + q8 * 4 + 3] = v.w;
    __syncthreads();
    ushort4 o;
    o.x = f2bf(tr[(q8 * 4 + 0) * 33 + tt]);
    o.y = f2bf(tr[(q8 * 4 + 1) * 33 + tt]);
    o.z = f2bf(tr[(q8 * 4 + 2) * 33 + tt]);
    o.w = f2bf(tr[(q8 * 4 + 3) * 33 + tt]);
    *(ushort4*)(dst + (jb * 32 + tt) * 32 + q8 * 4) = o;
    __syncthreads();
  }
}

// ---------------------------------------------------------------------------
// Attention (validated, byte-identical math to R12) with optional convw
// rider blocks: bid < 1024 -> attention pair-block; bid >= 1024 -> convw
// (out_w f32 -> bf16), 1024 blocks x 16384 f32 each. Rider blocks have no
// barriers/LDS use -> they fill CU memory-idle slots during attn compute.
// ---------------------------------------------------------------------------
__global__ __launch_bounds__(256, 2) void attn_convw(
    const float* __restrict__ qin, const unsigned short* __restrict__ KT2,
    const unsigned short* __restrict__ VT2, unsigned short* __restrict__ attn,
    const float* __restrict__ w, unsigned short* __restrict__ wbf,
    int nattn) {
  const int tid = threadIdx.x;
  int bid = blockIdx.x;

  if (bid >= nattn) {   // ---- convw rider ----
    const int b2 = bid - nattn;
#pragma unroll
    for (int it = 0; it < 8; ++it) {
      const int flat = b2 * 16384 + it * 2048 + tid * 8;
      const float4* s = (const float4*)(w + flat);
      float4 v0 = s[0], v1 = s[1];
      uint4 pk;
      pk.x = (unsigned)f2bf(v0.x) | ((unsigned)f2bf(v0.y) << 16);
      pk.y = (unsigned)f2bf(v0.z) | ((unsigned)f2bf(v0.w) << 16);
      pk.z = (unsigned)f2bf(v1.x) | ((unsigned)f2bf(v1.y) << 16);
      pk.w = (unsigned)f2bf(v1.z) | ((unsigned)f2bf(v1.w) << 16);
      *(uint4*)(wbf + flat) = pk;
    }
    return;
  }

  __shared__ __align__(16) unsigned short kv[8192];
  __shared__ __align__(16) unsigned short plds[4 * 16 * 264];

  const int lane = tid & 63;
  const int wave = tid >> 6;
  const int li   = lane & 15;
  const int ks   = lane >> 4;

  const int pp  = (bid & 7) * 32 + ((bid >> 3) & 31);
  const int ib  = bid >> 8;
  const int x = pp >> 4, y = pp & 15;
  const int i0 = ib * 64 + wave * 16;

  bf16x8 qf[8];
  {
    const float* qrow = qin + ((size_t)(y * 256 + i0 + li)) * 4096 + x * 256 + ks * 8;
#pragma unroll
    for (int s = 0; s < 8; ++s) {
      float4 v0 = *(const float4*)(qrow + s * 32);
      float4 v1 = *(const float4*)(qrow + s * 32 + 4);
      union { bf16x8 v; unsigned short u[8]; } t;
      t.u[0] = f2bf(v0.x * 0.0625f); t.u[1] = f2bf(v0.y * 0.0625f);
      t.u[2] = f2bf(v0.z * 0.0625f); t.u[3] = f2bf(v0.w * 0.0625f);
      t.u[4] = f2bf(v1.x * 0.0625f); t.u[5] = f2bf(v1.y * 0.0625f);
      t.u[6] = f2bf(v1.z * 0.0625f); t.u[7] = f2bf(v1.w * 0.0625f);
      qf[s] = t.v;
    }
  }

  const f32x4 vzero = {0.f, 0.f, 0.f, 0.f};
  f32x4 sacc[16];
#pragma unroll
  for (int f = 0; f < 16; ++f) sacc[f] = vzero;

  const unsigned short* ktile = KT2 + (size_t)pp * 65536;
#pragma unroll
  for (int s = 0; s < 8; ++s) {
    __syncthreads();
#pragma unroll
    for (int cc = 0; cc < 4; ++cc) {
      const unsigned short* g = ktile + (size_t)s * 8192 + (cc * 256 + tid) * 8;
      __builtin_amdgcn_global_load_lds((AS1 unsigned int*)g,
          (AS3 unsigned int*)((AS3 char*)kv + cc * 4096 + wave * 1024), 16, 0, 0);
    }
    __syncthreads();
#pragma unroll
    for (int f = 0; f < 16; ++f) {
      bf16x8 bfr = *(const bf16x8*)&kv[(f * 16 + li) * 32 + ks * 8];
      sacc[f] = __builtin_amdgcn_mfma_f32_16x16x32_bf16(qf[s], bfr, sacc[f], 0, 0, 0);
    }
  }

  float sm[4];
#pragma unroll
  for (int qi = 0; qi < 4; ++qi) {
    float m = sacc[0][qi];
#pragma unroll
    for (int f = 1; f < 16; ++f) m = fmaxf(m, sacc[f][qi]);
    m = fmaxf(m, __shfl_xor(m, 1));
    m = fmaxf(m, __shfl_xor(m, 2));
    m = fmaxf(m, __shfl_xor(m, 4));
    m = fmaxf(m, __shfl_xor(m, 8));
    float ssum = 0.f;
#pragma unroll
    for (int f = 0; f < 16; ++f) {
      float pv = __expf(sacc[f][qi] - m);
      sacc[f][qi] = pv;
      ssum += pv;
    }
    ssum += __shfl_xor(ssum, 1);
    ssum += __shfl_xor(ssum, 2);
    ssum += __shfl_xor(ssum, 4);
    ssum += __shfl_xor(ssum, 8);
    sm[qi] = ssum;
  }

  unsigned short* pw = plds + wave * 4224;
#pragma unroll
  for (int f = 0; f < 16; ++f)
#pragma unroll
    for (int qi = 0; qi < 4; ++qi)
      pw[(ks * 4 + qi) * 264 + f * 16 + li] = f2bf(sacc[f][qi]);

  f32x4 oacc[16];
#pragma unroll
  for (int f = 0; f < 16; ++f) oacc[f] = vzero;
  const unsigned short* vtile = VT2 + (size_t)pp * 65536;
  const unsigned short* pr = plds + wave * 4224 + li * 264;
#pragma unroll
  for (int s2 = 0; s2 < 8; ++s2) {
    __syncthreads();
#pragma unroll
    for (int cc = 0; cc < 4; ++cc) {
      const unsigned short* g = vtile + (size_t)s2 * 8192 + (cc * 256 + tid) * 8;
      __builtin_amdgcn_global_load_lds((AS1 unsigned int*)g,
          (AS3 unsigned int*)((AS3 char*)kv + cc * 4096 + wave * 1024), 16, 0, 0);
    }
    __syncthreads();
    bf16x8 afr = *(const bf16x8*)&pr[s2 * 32 + ks * 8];
#pragma unroll
    for (int f = 0; f < 16; ++f) {
      bf16x8 bfr = *(const bf16x8*)&kv[(f * 16 + li) * 32 + ks * 8];
      oacc[f] = __builtin_amdgcn_mfma_f32_16x16x32_bf16(afr, bfr, oacc[f], 0, 0, 0);
    }
  }

  float rs4[4];
#pragma unroll
  for (int qi = 0; qi < 4; ++qi) rs4[qi] = 1.0f / sm[qi];
  unsigned short* abase = attn + (size_t)(x * 256 + i0 + ks * 4) * 4096 + y * 256 + li;
#pragma unroll
  for (int f = 0; f < 16; ++f)
#pragma unroll
    for (int qi = 0; qi < 4; ++qi)
      abase[(size_t)qi * 4096 + f * 16] = f2bf(oacc[f][qi] * rs4[qi]);
}

// ---------------------------------------------------------------------------
// Standalone convw (fallback when ws_size < 128 MB: runs after attn, wbf
// aliases KT2 exactly as in R12).
// ---------------------------------------------------------------------------
__global__ __launch_bounds__(256) void convw(const float* __restrict__ w,
                                             unsigned short* __restrict__ o) {
  const int i = blockIdx.x * 256 + threadIdx.x;
  const float4* s = (const float4*)w + (size_t)i * 2;
  float4 v0 = s[0], v1 = s[1];
  uint4 pk;
  pk.x = (unsigned)f2bf(v0.x) | ((unsigned)f2bf(v0.y) << 16);
  pk.y = (unsigned)f2bf(v0.z) | ((unsigned)f2bf(v0.w) << 16);
  pk.z = (unsigned)f2bf(v1.x) | ((unsigned)f2bf(v1.y) << 16);
  pk.w = (unsigned)f2bf(v1.z) | ((unsigned)f2bf(v1.w) << 16);
  *((uint4*)o + i) = pk;
}

// ---------------------------------------------------------------------------
// 256x256xBK=64 GEMM (FROZEN: best measured, 118.6us / 1160 TF, R12).
// Ring-2 LDS (2 x 64KB), ONE barrier per K-tile; 64B rows + XOR swizzle
// (PMC: 0 bank conflicts); staging via global_load_lds w16, counted-vmcnt
// certification. See R6 ablation + R7-R12 post-mortems for why this is the
// structure-family floor (~46% dense; MFMA 2163 + ~2300 residual per tile
// invariant under barrier count / phase structure / occupancy / A-path).
// ---------------------------------------------------------------------------
__global__ __launch_bounds__(512, 2) void proj_gemm64(
    const unsigned short* __restrict__ A, const unsigned short* __restrict__ W,
    const float* __restrict__ bias, float* __restrict__ out) {
  __shared__ __align__(1024) char lds[131072];  // 2 bufs x (A 32K | B 32K)

  const int tid  = threadIdx.x;
  const int lane = tid & 63;
  const int w    = tid >> 6;
  const int li   = lane & 15;
  const int ks   = lane >> 4;
  const int wr   = w >> 2;          // 0..1 (M half)
  const int wc   = w & 3;           // 0..3 (N quarter)
  const int LB   = (li * 64 + ks * 16) ^ (((li >> 3) & 1) << 5);

  const int bid = blockIdx.x;
  const int swz = (bid & 7) * 32 + (bid >> 3);      // XCD swizzle, 256 % 8 == 0
  const int m0b = (swz >> 4) * 256, n0b = (swz & 15) * 256;

  unsigned sA[2], sB[2];
  int dstP[2];
#pragma unroll
  for (int j = 0; j < 2; ++j) {
    int P = j * 8192 + tid * 16;
    int L = P ^ (((P >> 9) & 1) << 5);              // involution
    int row = L >> 6, col = L & 63;
    dstP[j] = P;
    sA[j] = (unsigned)((m0b + row) * 8192 + col);
    sB[j] = (unsigned)((n0b + row) * 8192 + col);
  }
  const char* Ac = (const char*)A;
  const char* Wc = (const char*)W;
  AS3 char* L3 = (AS3 char*)lds;

  const f32x4 vzero = {0.f, 0.f, 0.f, 0.f};
  f32x4 acc[8][4];
#pragma unroll
  for (int m = 0; m < 8; ++m)
#pragma unroll
    for (int n = 0; n < 4; ++n) acc[m][n] = vzero;

#define STG_A(kt, buf, kk) do {                                                \
    const unsigned _o = (unsigned)(kt) * 128u + (unsigned)(kk) * 64u;          \
    _Pragma("unroll") for (int j = 0; j < 2; ++j)                              \
      __builtin_amdgcn_global_load_lds((AS1 unsigned int*)(Ac + sA[j] + _o),   \
          (AS3 unsigned int*)(L3 + (buf) + (kk) * 16384 + dstP[j]), 16, 0, 0); \
  } while (0)
#define STG_B(kt, buf, kk) do {                                                \
    const unsigned _o = (unsigned)(kt) * 128u + (unsigned)(kk) * 64u;          \
    _Pragma("unroll") for (int j = 0; j < 2; ++j)                              \
      __builtin_amdgcn_global_load_lds((AS1 unsigned int*)(Wc + sB[j] + _o),   \
          (AS3 unsigned int*)(L3 + (buf) + 32768 + (kk) * 16384 + dstP[j]),    \
          16, 0, 0);                                                           \
  } while (0)
#define RD_A(buf, kk, m) (*(const bf16x8*)(lds + (buf) + (kk) * 16384 +        \
                                           wr * 8192 + (m) * 1024 + LB))
#define RD_B(buf, kk, n) (*(const bf16x8*)(lds + (buf) + 32768 + (kk) * 16384 + \
                                           wc * 4096 + (n) * 1024 + LB))
#define MFMA(a, b, c) __builtin_amdgcn_mfma_f32_16x16x32_bf16((a), (b), (c), 0, 0, 0)

  // ---- prologue: tile 0 -> buf 0 ----
  STG_A(0, 0, 0); STG_A(0, 0, 1); STG_B(0, 0, 0); STG_B(0, 0, 1);
  asm volatile("s_waitcnt vmcnt(0)" ::: "memory");
  __builtin_amdgcn_s_barrier();

  for (int t = 0; t < 64; ++t) {
    const int cur = (t & 1) * 65536;
    const int oth = 65536 - cur;
    const int k1  = (t < 63) ? t + 1 : 63;          // clamped tail: dead buf
    bf16x8 af[8], bf[4];

    // ---- sub-phase 0 (kk=0): stage A(t+1); reads; MFMA ----
    STG_A(k1, oth, 0); STG_A(k1, oth, 1);
    af[0] = RD_A(cur, 0, 0);
#pragma unroll
    for (int n = 0; n < 4; ++n) bf[n] = RD_B(cur, 0, n);
#pragma unroll
    for (int m = 1; m < 8; ++m) af[m] = RD_A(cur, 0, m);
    __builtin_amdgcn_s_setprio(1);
#pragma unroll
    for (int m = 0; m < 8; ++m)
#pragma unroll
      for (int n = 0; n < 4; ++n)
        acc[m][n] = MFMA(af[m], bf[n], acc[m][n]);
    __builtin_amdgcn_s_setprio(0);

    // ---- sub-phase 1 (kk=1): stage B(t+1); reads; MFMA ----
    STG_B(k1, oth, 0); STG_B(k1, oth, 1);
    af[0] = RD_A(cur, 1, 0);
#pragma unroll
    for (int n = 0; n < 4; ++n) bf[n] = RD_B(cur, 1, n);
#pragma unroll
    for (int m = 1; m < 8; ++m) af[m] = RD_A(cur, 1, m);
    __builtin_amdgcn_s_setprio(1);
#pragma unroll
    for (int m = 0; m < 8; ++m)
#pragma unroll
      for (int n = 0; n < 4; ++n)
        acc[m][n] = MFMA(af[m], bf[n], acc[m][n]);
    __builtin_amdgcn_s_setprio(0);

    asm volatile("s_waitcnt vmcnt(0)" ::: "memory");  // stage(t+1) complete
    __builtin_amdgcn_s_barrier();
  }

  // ---- epilogue ----
  float bv[4];
#pragma unroll
  for (int n = 0; n < 4; ++n) bv[n] = bias[n0b + wc * 64 + n * 16 + li];
#pragma unroll
  for (int m = 0; m < 8; ++m) {
#pragma unroll
    for (int qi = 0; qi < 4; ++qi) {
      const int row = m0b + wr * 128 + m * 16 + ks * 4 + qi;
      float* orow = out + (size_t)row * 4096 + n0b + wc * 64 + li;
#pragma unroll
      for (int n = 0; n < 4; ++n) orow[n * 16] = acc[m][n][qi] + bv[n];
    }
  }
#undef STG_A
#undef STG_B
#undef RD_A
#undef RD_B
#undef MFMA
}

// ---------------------------------------------------------------------------
extern "C" void kernel_launch(void* const* d_in, const int* in_sizes, int n_in,
                              void* d_out, int out_size, void* d_ws, size_t ws_size,
                              hipStream_t stream) {
  const float* q = (const float*)d_in[0];
  const float* k = (const float*)d_in[1];
  const float* v = (const float*)d_in[2];
  const float* w = (const float*)d_in[3];
  const float* b = (const float*)d_in[4];
  float* out = (float*)d_out;
  char* ws = (char*)d_ws;

  unsigned short* attn = (unsigned short*)ws;                      // 32 MB
  unsigned short* KT2  = (unsigned short*)(ws + (size_t)33554432); // 32 MB
  unsigned short* VT2  = (unsigned short*)(ws + (size_t)67108864); // 32 MB

  kv_transpose<<<dim3(2048, 2), 256, 0, stream>>>(k, v, KT2, VT2);

  if (ws_size >= (size_t)134217728) {
    // wbf gets its own region -> convw rides inside the attn launch (overlap)
    unsigned short* wbf = (unsigned short*)(ws + (size_t)100663296); // 32 MB
    attn_convw<<<2048, 256, 0, stream>>>(q, KT2, VT2, attn, w, wbf, 1024);
    proj_gemm64<<<256, 512, 0, stream>>>(attn, wbf, b, out);
  } else {
    // fallback = exact R12 ordering (wbf aliases KT2 after attn is done)
    unsigned short* wbf = KT2;
    attn_convw<<<1024, 256, 0, stream>>>(q, KT2, VT2, attn, w, wbf, 1024);
    convw<<<8192, 256, 0, stream>>>(w, wbf);
    proj_gemm64<<<256, 512, 0, stream>>>(attn, wbf, b, out);
  }
}